// Round 9
// baseline (936.291 us; speedup 1.0000x reference)
//
#include <hip/hip_runtime.h>
#include <hip/hip_bf16.h>
#include <stdint.h>

#define NN 100000
#define NE 1600000
#define FD 128
#define CD 40
#define NL 4
#define NTB 391        // coarse buckets of 256 nodes (391*256 = 100096)
#define TILE 4096      // edges per staging block
#define NTILES 391     // ceil(NE/TILE)
#define EBCAP 8192     // per-bucket staged region (entries incl. 16-pad)
#define OCAP 5120      // per-bucket csr region (real+pad4; det. max ~4800)
#define NREP 64        // BN-stats atomic replicas
#define RPB 376        // repack blocks: (NL*16384 + 5*6144)/256
#define PKB 512        // pack blocks (grid-strided)
#define GFCB 1563      // gfc grid (64 rows/block)

typedef __bf16 bf16;
typedef __bf16 bf16x8 __attribute__((ext_vector_type(8)));
typedef float f32x4 __attribute__((ext_vector_type(4)));

__device__ __forceinline__ unsigned short f2b(float f) {
  bf16 b = (bf16)f;
  unsigned short u;
  __builtin_memcpy(&u, &b, 2);
  return u;
}
__device__ __forceinline__ float lo16(unsigned int u) { return __uint_as_float(u << 16); }
__device__ __forceinline__ float hi16(unsigned int u) { return __uint_as_float(u & 0xffff0000u); }

// ---------- pass 1: LDS-staged binning + (merged) weight repack ----------
__launch_bounds__(256)
__global__ void k_bfill(const int* __restrict__ src, const int* __restrict__ dst,
                        int* __restrict__ gcur, unsigned int* __restrict__ csrE,
                        const float* __restrict__ wc, const float* __restrict__ wf,
                        bf16* __restrict__ wp, bf16* __restrict__ wpfc) {
  __shared__ int cnt[NTB], pref[NTB], gofs[NTB];
  __shared__ int sc[512];
  __shared__ unsigned int stage[TILE];
  __shared__ unsigned short tgtb[TILE];
  int tid = threadIdx.x;
  if (blockIdx.x >= NTILES) {
    // ---- weight repack part (independent of edges) ----
    int t = (blockIdx.x - NTILES) * 256 + tid;
    if (t < NL * 16384) {
      int j = t & 7, lane = (t >> 3) & 63, n0 = (t >> 9) & 7, k0 = (t >> 12) & 3, layer = t >> 14;
      int k = k0 * 32 + (lane >> 4) * 8 + j;
      int n = n0 * 16 + (lane & 15);
      wp[t] = (bf16)wc[(layer * 128 + k) * 128 + n];
    } else {
      t -= NL * 16384;
      if (t < 5 * 6144) {
        int j = t & 7, lane = (t >> 3) & 63;
        int rest = t >> 9;
        int n0 = rest % 3;
        int rest2 = rest / 3;
        int k0 = rest2 & 3, layer = rest2 >> 2;
        int k = k0 * 32 + (lane >> 4) * 8 + j;
        int n = n0 * 16 + (lane & 15);
        wpfc[t] = (n < CD) ? (bf16)wf[(layer * 128 + k) * CD + n] : (bf16)0.0f;
      }
    }
    return;
  }
  int base = blockIdx.x * TILE;
  int tcnt = min(TILE, NE - base);
  for (int b = tid; b < NTB; b += 256) cnt[b] = 0;
  __syncthreads();
  unsigned int pay[16];
  int brk[16];
#pragma unroll
  for (int i = 0; i < 16; i++) {
    int e = base + tid + i * 256;
    if (e < NE) {
      int d = dst[e];
      int b = d >> 8;
      int r = atomicAdd(&cnt[b], 1);
      pay[i] = (unsigned int)src[e] | ((unsigned int)(d & 255) << 17);
      brk[i] = (b << 12) | r;
    } else {
      brk[i] = -1;
    }
  }
  __syncthreads();
  sc[tid] = (tid < NTB) ? cnt[tid] : 0;
  sc[tid + 256] = (tid + 256 < NTB) ? cnt[tid + 256] : 0;
  __syncthreads();
  for (int off = 1; off < 512; off <<= 1) {
    int a0 = (tid >= off) ? sc[tid - off] : 0;
    int a1 = sc[tid + 256 - off];
    __syncthreads();
    sc[tid] += a0;
    sc[tid + 256] += a1;
    __syncthreads();
  }
  for (int b = tid; b < NTB; b += 256) pref[b] = sc[b] - cnt[b];
  __syncthreads();
#pragma unroll
  for (int i = 0; i < 16; i++) {
    if (brk[i] >= 0) {
      int b = brk[i] >> 12, r = brk[i] & 4095;
      int p = pref[b] + r;
      if ((unsigned)p < (unsigned)TILE) {
        stage[p] = pay[i];
        tgtb[p] = (unsigned short)b;
      }
    }
  }
  for (int b = tid; b < NTB; b += 256) {
    int c = cnt[b];
    gofs[b] = c ? atomicAdd(&gcur[b], (c + 15) & ~15) : 0;
  }
  __syncthreads();
  for (int t = tid; t < tcnt; t += 256) {
    int b = tgtb[t];
    int pos = gofs[b] + (t - pref[b]);
    if ((unsigned)pos < (unsigned)EBCAP) csrE[(size_t)b * EBCAP + pos] = stage[t];
  }
  for (int b = tid; b < NTB; b += 256) {
    int c = cnt[b];
    if (c) {
      int pad = (c + 15) & ~15;
      for (int j = c; j < pad; j++) {
        int pos = gofs[b] + j;
        if ((unsigned)pos < (unsigned)EBCAP) csrE[(size_t)b * EBCAP + pos] = 0xFFFFFFFFu;
      }
    }
  }
}

// ---------- pass 2: per-bucket counting sort; per-node lists padded to x4 ----------
__launch_bounds__(256)
__global__ void k_bsort(const int* __restrict__ gcur, const unsigned int* __restrict__ csrE,
                        unsigned int* __restrict__ csrp, float* __restrict__ dinv,
                        int2* __restrict__ rse) {
  __shared__ unsigned int ent[OCAP];
  __shared__ int c32[256], prefn[256], c2[256], sc[256];
  __shared__ int ecnt_s;
  int b = blockIdx.x, tid = threadIdx.x;
  c32[tid] = 0;
  c2[tid] = 0;
  if (tid == 0) ecnt_s = 0;
  __syncthreads();
  int claimed = min(gcur[b], EBCAP);
  const unsigned int* in = csrE + (size_t)b * EBCAP;
  for (int i = tid; i < claimed; i += 256) {
    unsigned int e = in[i];
    if (e != 0xFFFFFFFFu) {
      int idx = atomicAdd(&ecnt_s, 1);
      if (idx < OCAP) ent[idx] = e;
      atomicAdd(&c32[e >> 17], 1);
    }
  }
  __syncthreads();
  int cnt = min(ecnt_s, OCAP);
  int c = c32[tid];
  int pc = (c + 3) & ~3;           // padded-to-multiple-of-4 length
  sc[tid] = pc;
  __syncthreads();
  for (int off = 1; off < 256; off <<= 1) {
    int a = (tid >= off) ? sc[tid - off] : 0;
    __syncthreads();
    sc[tid] += a;
    __syncthreads();
  }
  prefn[tid] = sc[tid] - pc;
  int node = b * 256 + tid;
  if (node < NN) {
    dinv[node] = rsqrtf((float)c + 2.0f);
    int s = b * OCAP + prefn[tid];
    rse[node] = make_int2(s, s + pc);
  }
  for (int j = c; j < pc; j++) {
    int pos = prefn[tid] + j;
    if (pos < OCAP) csrp[b * OCAP + pos] = 0x1FFFFu;
  }
  __syncthreads();
  for (int i = tid; i < cnt; i += 256) {
    unsigned int e = ent[i];
    int dlo = e >> 17;
    int ofs = atomicAdd(&c2[dlo], 1);
    int pos = prefn[dlo] + ofs;
    if (pos < OCAP) csrp[b * OCAP + pos] = e & 0x1FFFFu;
  }
}

// ---------- fused (BN+ReLU) -> [conv GEMM | FC head (+log_softmax)] (+merged pack) ----------
template <int NC, bool BN, bool INIT, bool LSM, bool PACK>
__launch_bounds__(256)
__global__ void k_gfc(const void* __restrict__ inp, const float* __restrict__ stats,
                      const float* __restrict__ g, const float* __restrict__ bb,
                      const bf16* __restrict__ wconv, const bf16* __restrict__ wfc,
                      const float* __restrict__ fcb, bf16* __restrict__ xwb,
                      float* __restrict__ out,
                      unsigned int* __restrict__ csrp, const float* __restrict__ dinvp) {
  __shared__ bf16 wl[NC * 2048 + 6144];
  __shared__ float sc[128], sh[128];
  int tid = threadIdx.x;
  if (PACK && blockIdx.x >= GFCB) {
    // ---- coef pre-pack (depends only on bsort) ----
    for (int i = (blockIdx.x - GFCB) * 256 + tid; i < NTB * OCAP; i += PKB * 256) {
      unsigned int e = csrp[i];
      unsigned int s = e & 0x1FFFFu;
      unsigned int fix = 0;
      if (s < NN) {
        fix = (unsigned int)__float2uint_rn(dinvp[s] * 32768.0f);
      } else {
        s = 0;
      }
      csrp[i] = (fix << 17) | s;
    }
    return;
  }
  if (NC) {
    const uint4* gc = (const uint4*)wconv;
    uint4* lc = (uint4*)wl;
#pragma unroll
    for (int i = 0; i < NC; i++) lc[tid + i * 256] = gc[tid + i * 256];
  }
  {
    const uint4* gf = (const uint4*)wfc;
    uint4* lf = (uint4*)(wl + NC * 2048);
    for (int i = tid; i < 768; i += 256) lf[i] = gf[i];
  }
  if (BN && tid < 128) {
    const float invN = 1.0f / (float)NN;
    float s1 = 0.f, s2 = 0.f;
#pragma unroll 8
    for (int r = 0; r < NREP; r++) {
      s1 += stats[r * 256 + tid];
      s2 += stats[r * 256 + 128 + tid];
    }
    float mu = s1 * invN;
    float var = s2 * invN - mu * mu;
    float s = g[tid] * rsqrtf(var + 1e-5f);
    sc[tid] = s;
    sh[tid] = bb[tid] - mu * s;
  }
  __syncthreads();
  int wid = tid >> 6, lane = tid & 63, quad = lane >> 4, l15 = lane & 15;
  int m_base = blockIdx.x * 64 + wid * 16;
  int arow = m_base + l15;
  if (arow >= NN) arow = NN - 1;
  f32x4 accc[NC > 0 ? NC : 1];
  f32x4 accf[3];
  if (NC) {
#pragma unroll
    for (int i = 0; i < NC; i++) accc[i] = (f32x4){0.f, 0.f, 0.f, 0.f};
  }
#pragma unroll
  for (int i = 0; i < 3; i++) accf[i] = (f32x4){0.f, 0.f, 0.f, 0.f};
#pragma unroll
  for (int k0 = 0; k0 < 4; k0++) {
    union Fr { bf16x8 v; unsigned short us[8]; } fr;
    if (BN) {
      const uint4* prow = (const uint4*)((const bf16*)inp + (size_t)arow * 128 + k0 * 32 + quad * 8);
      uint4 u = *prow;
      unsigned int uu[4] = {u.x, u.y, u.z, u.w};
      int kc = k0 * 32 + quad * 8;
#pragma unroll
      for (int p = 0; p < 4; p++) {
        float x0 = lo16(uu[p]) * sc[kc + 2 * p] + sh[kc + 2 * p];
        float x1 = hi16(uu[p]) * sc[kc + 2 * p + 1] + sh[kc + 2 * p + 1];
        fr.us[2 * p] = f2b(fmaxf(0.f, x0));
        fr.us[2 * p + 1] = f2b(fmaxf(0.f, x1));
      }
    } else {
      const float* prow = (const float*)inp + (size_t)arow * 128 + k0 * 32 + quad * 8;
      float4 u0 = *(const float4*)prow;
      float4 u1 = *(const float4*)(prow + 4);
      fr.us[0] = f2b(u0.x); fr.us[1] = f2b(u0.y); fr.us[2] = f2b(u0.z); fr.us[3] = f2b(u0.w);
      fr.us[4] = f2b(u1.x); fr.us[5] = f2b(u1.y); fr.us[6] = f2b(u1.z); fr.us[7] = f2b(u1.w);
    }
    bf16x8 a = fr.v;
    if (NC) {
#pragma unroll
      for (int n0 = 0; n0 < NC; n0++) {
        bf16x8 bfr = *reinterpret_cast<const bf16x8*>(&wl[(k0 * NC + n0) * 512 + lane * 8]);
        accc[n0] = __builtin_amdgcn_mfma_f32_16x16x32_bf16(a, bfr, accc[n0], 0, 0, 0);
      }
    }
#pragma unroll
    for (int n0 = 0; n0 < 3; n0++) {
      bf16x8 bfr = *reinterpret_cast<const bf16x8*>(&wl[NC * 2048 + (k0 * 3 + n0) * 512 + lane * 8]);
      accf[n0] = __builtin_amdgcn_mfma_f32_16x16x32_bf16(a, bfr, accf[n0], 0, 0, 0);
    }
  }
  int orow = m_base + quad * 4;
  if (NC) {
#pragma unroll
    for (int n0 = 0; n0 < NC; n0++) {
#pragma unroll
      for (int r2 = 0; r2 < 4; r2++) {
        int row = orow + r2;
        if (row < NN) xwb[(size_t)row * 128 + n0 * 16 + l15] = (bf16)accc[n0][r2];
      }
    }
  }
  if (!LSM) {
#pragma unroll
    for (int n0 = 0; n0 < 3; n0++) {
      int col = n0 * 16 + l15;
      if (col < CD) {
        float bias = fcb[col];
#pragma unroll
        for (int r2 = 0; r2 < 4; r2++) {
          int row = orow + r2;
          if (row < NN) {
            size_t idx = (size_t)row * CD + col;
            float v = accf[n0][r2] + bias;
            out[idx] = INIT ? v : out[idx] + v;
          }
        }
      }
    }
  } else {
    float bias[3];
#pragma unroll
    for (int n0 = 0; n0 < 3; n0++) {
      int col = n0 * 16 + l15;
      bias[n0] = (col < CD) ? fcb[col] : 0.f;
    }
#pragma unroll
    for (int r2 = 0; r2 < 4; r2++) {
      int row = orow + r2;
      float v[3];
#pragma unroll
      for (int n0 = 0; n0 < 3; n0++) {
        int col = n0 * 16 + l15;
        if (col < CD) {
          float prev = (row < NN) ? out[(size_t)row * CD + col] : 0.f;
          v[n0] = prev + accf[n0][r2] + bias[n0];
        } else {
          v[n0] = -1e30f;
        }
      }
      float m = fmaxf(v[0], fmaxf(v[1], v[2]));
#pragma unroll
      for (int s = 1; s < 16; s <<= 1) m = fmaxf(m, __shfl_xor(m, s, 64));
      float sum = 0.f;
#pragma unroll
      for (int n0 = 0; n0 < 3; n0++) {
        int col = n0 * 16 + l15;
        if (col < CD) sum += __expf(v[n0] - m);
      }
#pragma unroll
      for (int s = 1; s < 16; s <<= 1) sum += __shfl_xor(sum, s, 64);
      float ls = m + logf(sum);
      if (row < NN) {
#pragma unroll
        for (int n0 = 0; n0 < 3; n0++) {
          int col = n0 * 16 + l15;
          if (col < CD) out[(size_t)row * CD + col] = v[n0] - ls;
        }
      }
    }
  }
}

// ---------- CSR gather: 1 wave = 1 node; uint4 loads; fused BN-stats epilogue ----------
__launch_bounds__(256)
__global__ void k_gather(const uint4* __restrict__ xw, const int2* __restrict__ rse,
                         const unsigned int* __restrict__ csrp, const float* __restrict__ dinv,
                         uint4* __restrict__ aggb, float* __restrict__ statsL) {
  __shared__ float ls1[128], ls2[128];
  int tid = threadIdx.x;
  if (tid < 128) { ls1[tid] = 0.f; ls2[tid] = 0.f; }
  __syncthreads();
  int n = blockIdx.x * 4 + (tid >> 6);
  int l = tid & 63;
  int h = l >> 4, cl = l & 15;    // 4 edge-slots x 16 lanes; 16 lanes x 16B = 256B row
  float dn = dinv[n];
  float kk = dn * (1.0f / 32768.0f);
  uint4 u = xw[n * 16 + cl];
  float cs = (h == 0) ? 2.0f * dn * dn : 0.0f;
  float a0 = cs * lo16(u.x), a1 = cs * hi16(u.x);
  float a2 = cs * lo16(u.y), a3 = cs * hi16(u.y);
  float a4 = cs * lo16(u.z), a5 = cs * hi16(u.z);
  float a6 = cs * lo16(u.w), a7 = cs * hi16(u.w);
  int2 r = rse[n];
  int e = r.x, e1 = r.y;   // length multiple of 4
  for (; e + 7 < e1; e += 8) {
    unsigned int p0 = csrp[e + h];
    unsigned int p1 = csrp[e + 4 + h];
    uint4 v0 = xw[(p0 & 0x1FFFFu) * 16 + cl];
    uint4 v1 = xw[(p1 & 0x1FFFFu) * 16 + cl];
    float c0 = (float)(p0 >> 17) * kk;
    float c1 = (float)(p1 >> 17) * kk;
    a0 += c0 * lo16(v0.x); a1 += c0 * hi16(v0.x);
    a2 += c0 * lo16(v0.y); a3 += c0 * hi16(v0.y);
    a4 += c0 * lo16(v0.z); a5 += c0 * hi16(v0.z);
    a6 += c0 * lo16(v0.w); a7 += c0 * hi16(v0.w);
    a0 += c1 * lo16(v1.x); a1 += c1 * hi16(v1.x);
    a2 += c1 * lo16(v1.y); a3 += c1 * hi16(v1.y);
    a4 += c1 * lo16(v1.z); a5 += c1 * hi16(v1.z);
    a6 += c1 * lo16(v1.w); a7 += c1 * hi16(v1.w);
  }
  if (e < e1) {
    unsigned int p0 = csrp[e + h];
    uint4 v0 = xw[(p0 & 0x1FFFFu) * 16 + cl];
    float c0 = (float)(p0 >> 17) * kk;
    a0 += c0 * lo16(v0.x); a1 += c0 * hi16(v0.x);
    a2 += c0 * lo16(v0.y); a3 += c0 * hi16(v0.y);
    a4 += c0 * lo16(v0.z); a5 += c0 * hi16(v0.z);
    a6 += c0 * lo16(v0.w); a7 += c0 * hi16(v0.w);
  }
  a0 += __shfl_xor(a0, 16, 64); a0 += __shfl_xor(a0, 32, 64);
  a1 += __shfl_xor(a1, 16, 64); a1 += __shfl_xor(a1, 32, 64);
  a2 += __shfl_xor(a2, 16, 64); a2 += __shfl_xor(a2, 32, 64);
  a3 += __shfl_xor(a3, 16, 64); a3 += __shfl_xor(a3, 32, 64);
  a4 += __shfl_xor(a4, 16, 64); a4 += __shfl_xor(a4, 32, 64);
  a5 += __shfl_xor(a5, 16, 64); a5 += __shfl_xor(a5, 32, 64);
  a6 += __shfl_xor(a6, 16, 64); a6 += __shfl_xor(a6, 32, 64);
  a7 += __shfl_xor(a7, 16, 64); a7 += __shfl_xor(a7, 32, 64);
  if (h == 0) {
    uint4 o;
    o.x = (unsigned int)f2b(a0) | ((unsigned int)f2b(a1) << 16);
    o.y = (unsigned int)f2b(a2) | ((unsigned int)f2b(a3) << 16);
    o.z = (unsigned int)f2b(a4) | ((unsigned int)f2b(a5) << 16);
    o.w = (unsigned int)f2b(a6) | ((unsigned int)f2b(a7) << 16);
    aggb[n * 16 + cl] = o;
    // fused BN-stats: accumulate this node's 8 columns into block LDS
    int cb = cl * 8;
    atomicAdd(&ls1[cb + 0], a0); atomicAdd(&ls2[cb + 0], a0 * a0);
    atomicAdd(&ls1[cb + 1], a1); atomicAdd(&ls2[cb + 1], a1 * a1);
    atomicAdd(&ls1[cb + 2], a2); atomicAdd(&ls2[cb + 2], a2 * a2);
    atomicAdd(&ls1[cb + 3], a3); atomicAdd(&ls2[cb + 3], a3 * a3);
    atomicAdd(&ls1[cb + 4], a4); atomicAdd(&ls2[cb + 4], a4 * a4);
    atomicAdd(&ls1[cb + 5], a5); atomicAdd(&ls2[cb + 5], a5 * a5);
    atomicAdd(&ls1[cb + 6], a6); atomicAdd(&ls2[cb + 6], a6 * a6);
    atomicAdd(&ls1[cb + 7], a7); atomicAdd(&ls2[cb + 7], a7 * a7);
  }
  __syncthreads();
  if (tid < 128) {
    float* st = statsL + (blockIdx.x & (NREP - 1)) * 256;
    atomicAdd(&st[tid], ls1[tid]);
    atomicAdd(&st[128 + tid], ls2[tid]);
  }
}

static inline size_t alup(size_t x) { return (x + 255) & ~(size_t)255; }

extern "C" void kernel_launch(void* const* d_in, const int* in_sizes, int n_in,
                              void* d_out, int out_size, void* d_ws, size_t ws_size,
                              hipStream_t stream) {
  char* p = (char*)d_ws;
  bf16* xwb = (bf16*)p;     p += alup((size_t)NN * FD * 2);
  bf16* aggb = (bf16*)p;    p += alup((size_t)NN * FD * 2);
  float* dinv = (float*)p;  p += alup((size_t)NN * 4);
  int2* rse = (int2*)p;     p += alup((size_t)NN * 8);
  int* gcur = (int*)p;      p += alup((size_t)NTB * 4);
  float* stats = (float*)p; p += alup((size_t)NL * NREP * 256 * 4);
  unsigned int* csrE = (unsigned int*)p; p += alup((size_t)NTB * EBCAP * 4);
  unsigned int* csrp = (unsigned int*)p; p += alup((size_t)NTB * OCAP * 4);
  bf16* wp = (bf16*)p;      p += alup((size_t)NL * 16384 * 2);
  bf16* wpfc = (bf16*)p;    p += alup((size_t)5 * 6144 * 2);

  const float* x = (const float*)d_in[0];
  const int* ei = (const int*)d_in[1];
  const int* srcv = ei;
  const int* dstv = ei + NE;
  const float* convw = (const float*)d_in[2];
  const float* bng = (const float*)d_in[4];
  const float* bnb = (const float*)d_in[5];
  const float* fcw = (const float*)d_in[6];
  const float* fcb = (const float*)d_in[7];
  float* out = (float*)d_out;

  // one memset over contiguous gcur + stats
  hipMemsetAsync(gcur, 0, alup((size_t)NTB * 4) + alup((size_t)NL * NREP * 256 * 4), stream);
  // build pass 1 + weight repack (independent halves of one grid)
  k_bfill<<<NTILES + RPB, 256, 0, stream>>>(srcv, dstv, gcur, csrE, convw, fcw, wp, wpfc);
  k_bsort<<<NTB, 256, 0, stream>>>(gcur, csrE, csrp, dinv, rse);
  // layer-0 conv GEMM + fc head (out init) + merged coef pre-pack
  k_gfc<8, false, true, false, true><<<GFCB + PKB, 256, 0, stream>>>(
      x, nullptr, nullptr, nullptr, wp, wpfc, fcb, xwb, out, csrp, dinv);

  for (int L = 0; L < NL; L++) {
    float* st = stats + (size_t)L * NREP * 256;
    k_gather<<<NN / 4, 256, 0, stream>>>((const uint4*)xwb, rse, csrp, dinv,
                                         (uint4*)aggb, st);
    if (L < NL - 1) {
      k_gfc<8, true, false, false, false><<<GFCB, 256, 0, stream>>>(
          aggb, st, bng + L * FD, bnb + L * FD,
          wp + (size_t)(L + 1) * 16384, wpfc + (size_t)(L + 1) * 6144,
          fcb + (L + 1) * CD, xwb, out, nullptr, nullptr);
    } else {
      k_gfc<0, true, false, true, false><<<GFCB, 256, 0, stream>>>(
          aggb, st, bng + L * FD, bnb + L * FD,
          nullptr, wpfc + (size_t)(L + 1) * 6144,
          fcb + (L + 1) * CD, nullptr, out, nullptr, nullptr);
    }
  }
}

// Round 10
// 659.051 us; speedup vs baseline: 1.4207x; 1.4207x over previous
//
#include <hip/hip_runtime.h>
#include <hip/hip_bf16.h>
#include <stdint.h>

#define NN 100000
#define NE 1600000
#define FD 128
#define CD 40
#define NL 4
#define NTB 391        // coarse buckets of 256 nodes (391*256 = 100096)
#define TILE 4096      // edges per staging block
#define NTILES 391     // ceil(NE/TILE)
#define EBCAP 8192     // per-bucket staged region (entries incl. 16-pad)
#define OCAP 5632      // per-bucket csr region (real+pad8; mean ~4992, +5sd margin)
#define RPB 376        // repack blocks: (NL*16384 + 5*6144)/256
#define PKB 512        // pack blocks (grid-strided)
#define GFCB 1563      // gfc grid (64 rows/block)

typedef __bf16 bf16;
typedef __bf16 bf16x8 __attribute__((ext_vector_type(8)));
typedef float f32x4 __attribute__((ext_vector_type(4)));

__device__ __forceinline__ unsigned short f2b(float f) {
  bf16 b = (bf16)f;
  unsigned short u;
  __builtin_memcpy(&u, &b, 2);
  return u;
}
__device__ __forceinline__ float lo16(unsigned int u) { return __uint_as_float(u << 16); }
__device__ __forceinline__ float hi16(unsigned int u) { return __uint_as_float(u & 0xffff0000u); }

// ---------- pass 1: LDS-staged binning + (merged) weight repack ----------
__launch_bounds__(256)
__global__ void k_bfill(const int* __restrict__ src, const int* __restrict__ dst,
                        int* __restrict__ gcur, unsigned int* __restrict__ csrE,
                        const float* __restrict__ wc, const float* __restrict__ wf,
                        bf16* __restrict__ wp, bf16* __restrict__ wpfc) {
  __shared__ int cnt[NTB], pref[NTB], gofs[NTB];
  __shared__ int sc[512];
  __shared__ unsigned int stage[TILE];
  __shared__ unsigned short tgtb[TILE];
  int tid = threadIdx.x;
  if (blockIdx.x >= NTILES) {
    int t = (blockIdx.x - NTILES) * 256 + tid;
    if (t < NL * 16384) {
      int j = t & 7, lane = (t >> 3) & 63, n0 = (t >> 9) & 7, k0 = (t >> 12) & 3, layer = t >> 14;
      int k = k0 * 32 + (lane >> 4) * 8 + j;
      int n = n0 * 16 + (lane & 15);
      wp[t] = (bf16)wc[(layer * 128 + k) * 128 + n];
    } else {
      t -= NL * 16384;
      if (t < 5 * 6144) {
        int j = t & 7, lane = (t >> 3) & 63;
        int rest = t >> 9;
        int n0 = rest % 3;
        int rest2 = rest / 3;
        int k0 = rest2 & 3, layer = rest2 >> 2;
        int k = k0 * 32 + (lane >> 4) * 8 + j;
        int n = n0 * 16 + (lane & 15);
        wpfc[t] = (n < CD) ? (bf16)wf[(layer * 128 + k) * CD + n] : (bf16)0.0f;
      }
    }
    return;
  }
  int base = blockIdx.x * TILE;
  int tcnt = min(TILE, NE - base);
  for (int b = tid; b < NTB; b += 256) cnt[b] = 0;
  __syncthreads();
  unsigned int pay[16];
  int brk[16];
#pragma unroll
  for (int i = 0; i < 16; i++) {
    int e = base + tid + i * 256;
    if (e < NE) {
      int d = dst[e];
      int b = d >> 8;
      int r = atomicAdd(&cnt[b], 1);
      pay[i] = (unsigned int)src[e] | ((unsigned int)(d & 255) << 17);
      brk[i] = (b << 12) | r;
    } else {
      brk[i] = -1;
    }
  }
  __syncthreads();
  sc[tid] = (tid < NTB) ? cnt[tid] : 0;
  sc[tid + 256] = (tid + 256 < NTB) ? cnt[tid + 256] : 0;
  __syncthreads();
  for (int off = 1; off < 512; off <<= 1) {
    int a0 = (tid >= off) ? sc[tid - off] : 0;
    int a1 = sc[tid + 256 - off];
    __syncthreads();
    sc[tid] += a0;
    sc[tid + 256] += a1;
    __syncthreads();
  }
  for (int b = tid; b < NTB; b += 256) pref[b] = sc[b] - cnt[b];
  __syncthreads();
#pragma unroll
  for (int i = 0; i < 16; i++) {
    if (brk[i] >= 0) {
      int b = brk[i] >> 12, r = brk[i] & 4095;
      int p = pref[b] + r;
      if ((unsigned)p < (unsigned)TILE) {
        stage[p] = pay[i];
        tgtb[p] = (unsigned short)b;
      }
    }
  }
  for (int b = tid; b < NTB; b += 256) {
    int c = cnt[b];
    gofs[b] = c ? atomicAdd(&gcur[b], (c + 15) & ~15) : 0;
  }
  __syncthreads();
  for (int t = tid; t < tcnt; t += 256) {
    int b = tgtb[t];
    int pos = gofs[b] + (t - pref[b]);
    if ((unsigned)pos < (unsigned)EBCAP) csrE[(size_t)b * EBCAP + pos] = stage[t];
  }
  for (int b = tid; b < NTB; b += 256) {
    int c = cnt[b];
    if (c) {
      int pad = (c + 15) & ~15;
      for (int j = c; j < pad; j++) {
        int pos = gofs[b] + j;
        if ((unsigned)pos < (unsigned)EBCAP) csrE[(size_t)b * EBCAP + pos] = 0xFFFFFFFFu;
      }
    }
  }
}

// ---------- pass 2: per-bucket counting sort; per-node lists padded to x8 ----------
__launch_bounds__(256)
__global__ void k_bsort(const int* __restrict__ gcur, const unsigned int* __restrict__ csrE,
                        unsigned int* __restrict__ csrp, float* __restrict__ dinv,
                        int2* __restrict__ rse) {
  __shared__ unsigned int ent[OCAP];
  __shared__ int c32[256], prefn[256], c2[256], sc[256];
  __shared__ int ecnt_s;
  int b = blockIdx.x, tid = threadIdx.x;
  c32[tid] = 0;
  c2[tid] = 0;
  if (tid == 0) ecnt_s = 0;
  __syncthreads();
  int claimed = min(gcur[b], EBCAP);
  const unsigned int* in = csrE + (size_t)b * EBCAP;
  for (int i = tid; i < claimed; i += 256) {
    unsigned int e = in[i];
    if (e != 0xFFFFFFFFu) {
      int idx = atomicAdd(&ecnt_s, 1);
      if (idx < OCAP) ent[idx] = e;
      atomicAdd(&c32[e >> 17], 1);
    }
  }
  __syncthreads();
  int cnt = min(ecnt_s, OCAP);
  int c = c32[tid];
  int pc = (c + 7) & ~7;           // padded-to-multiple-of-8 length
  sc[tid] = pc;
  __syncthreads();
  for (int off = 1; off < 256; off <<= 1) {
    int a = (tid >= off) ? sc[tid - off] : 0;
    __syncthreads();
    sc[tid] += a;
    __syncthreads();
  }
  prefn[tid] = sc[tid] - pc;
  int node = b * 256 + tid;
  if (node < NN) {
    dinv[node] = rsqrtf((float)c + 2.0f);
    int s = b * OCAP + prefn[tid];
    rse[node] = make_int2(s, s + pc);
  }
  for (int j = c; j < pc; j++) {
    int pos = prefn[tid] + j;
    if (pos < OCAP) csrp[b * OCAP + pos] = 0x1FFFFu;
  }
  __syncthreads();
  for (int i = tid; i < cnt; i += 256) {
    unsigned int e = ent[i];
    int dlo = e >> 17;
    int ofs = atomicAdd(&c2[dlo], 1);
    int pos = prefn[dlo] + ofs;
    if (pos < OCAP) csrp[b * OCAP + pos] = e & 0x1FFFFu;
  }
}

// ---------- fused (BN+ReLU) -> [conv GEMM | FC head (+log_softmax)] (+merged pack) ----------
template <int NC, bool BN, bool INIT, bool LSM, bool PACK>
__launch_bounds__(256)
__global__ void k_gfc(const void* __restrict__ inp, const float* __restrict__ stats,
                      const float* __restrict__ g, const float* __restrict__ bb,
                      const bf16* __restrict__ wconv, const bf16* __restrict__ wfc,
                      const float* __restrict__ fcb, bf16* __restrict__ xwb,
                      float* __restrict__ out,
                      unsigned int* __restrict__ csrp, const float* __restrict__ dinvp) {
  __shared__ bf16 wl[NC * 2048 + 6144];
  __shared__ float sc[128], sh[128];
  int tid = threadIdx.x;
  if (PACK && blockIdx.x >= GFCB) {
    for (int i = (blockIdx.x - GFCB) * 256 + tid; i < NTB * OCAP; i += PKB * 256) {
      unsigned int e = csrp[i];
      unsigned int s = e & 0x1FFFFu;
      unsigned int fix = 0;
      if (s < NN) {
        fix = (unsigned int)__float2uint_rn(dinvp[s] * 32768.0f);
      } else {
        s = 0;
      }
      csrp[i] = (fix << 17) | s;
    }
    return;
  }
  if (NC) {
    const uint4* gc = (const uint4*)wconv;
    uint4* lc = (uint4*)wl;
#pragma unroll
    for (int i = 0; i < NC; i++) lc[tid + i * 256] = gc[tid + i * 256];
  }
  {
    const uint4* gf = (const uint4*)wfc;
    uint4* lf = (uint4*)(wl + NC * 2048);
    for (int i = tid; i < 768; i += 256) lf[i] = gf[i];
  }
  if (BN && tid < 128) {
    const float invN = 1.0f / (float)NN;
    float s1 = stats[tid] + stats[256 + tid] + stats[512 + tid] + stats[768 + tid];
    float s2 = stats[128 + tid] + stats[384 + tid] + stats[640 + tid] + stats[896 + tid];
    float mu = s1 * invN;
    float var = s2 * invN - mu * mu;
    float s = g[tid] * rsqrtf(var + 1e-5f);
    sc[tid] = s;
    sh[tid] = bb[tid] - mu * s;
  }
  __syncthreads();
  int wid = tid >> 6, lane = tid & 63, quad = lane >> 4, l15 = lane & 15;
  int m_base = blockIdx.x * 64 + wid * 16;
  int arow = m_base + l15;
  if (arow >= NN) arow = NN - 1;
  f32x4 accc[NC > 0 ? NC : 1];
  f32x4 accf[3];
  if (NC) {
#pragma unroll
    for (int i = 0; i < NC; i++) accc[i] = (f32x4){0.f, 0.f, 0.f, 0.f};
  }
#pragma unroll
  for (int i = 0; i < 3; i++) accf[i] = (f32x4){0.f, 0.f, 0.f, 0.f};
#pragma unroll
  for (int k0 = 0; k0 < 4; k0++) {
    union Fr { bf16x8 v; unsigned short us[8]; } fr;
    if (BN) {
      const uint4* prow = (const uint4*)((const bf16*)inp + (size_t)arow * 128 + k0 * 32 + quad * 8);
      uint4 u = *prow;
      unsigned int uu[4] = {u.x, u.y, u.z, u.w};
      int kc = k0 * 32 + quad * 8;
#pragma unroll
      for (int p = 0; p < 4; p++) {
        float x0 = lo16(uu[p]) * sc[kc + 2 * p] + sh[kc + 2 * p];
        float x1 = hi16(uu[p]) * sc[kc + 2 * p + 1] + sh[kc + 2 * p + 1];
        fr.us[2 * p] = f2b(fmaxf(0.f, x0));
        fr.us[2 * p + 1] = f2b(fmaxf(0.f, x1));
      }
    } else {
      const float* prow = (const float*)inp + (size_t)arow * 128 + k0 * 32 + quad * 8;
      float4 u0 = *(const float4*)prow;
      float4 u1 = *(const float4*)(prow + 4);
      fr.us[0] = f2b(u0.x); fr.us[1] = f2b(u0.y); fr.us[2] = f2b(u0.z); fr.us[3] = f2b(u0.w);
      fr.us[4] = f2b(u1.x); fr.us[5] = f2b(u1.y); fr.us[6] = f2b(u1.z); fr.us[7] = f2b(u1.w);
    }
    bf16x8 a = fr.v;
    if (NC) {
#pragma unroll
      for (int n0 = 0; n0 < NC; n0++) {
        bf16x8 bfr = *reinterpret_cast<const bf16x8*>(&wl[(k0 * NC + n0) * 512 + lane * 8]);
        accc[n0] = __builtin_amdgcn_mfma_f32_16x16x32_bf16(a, bfr, accc[n0], 0, 0, 0);
      }
    }
#pragma unroll
    for (int n0 = 0; n0 < 3; n0++) {
      bf16x8 bfr = *reinterpret_cast<const bf16x8*>(&wl[NC * 2048 + (k0 * 3 + n0) * 512 + lane * 8]);
      accf[n0] = __builtin_amdgcn_mfma_f32_16x16x32_bf16(a, bfr, accf[n0], 0, 0, 0);
    }
  }
  int orow = m_base + quad * 4;
  if (NC) {
#pragma unroll
    for (int n0 = 0; n0 < NC; n0++) {
#pragma unroll
      for (int r2 = 0; r2 < 4; r2++) {
        int row = orow + r2;
        if (row < NN) xwb[(size_t)row * 128 + n0 * 16 + l15] = (bf16)accc[n0][r2];
      }
    }
  }
  if (!LSM) {
#pragma unroll
    for (int n0 = 0; n0 < 3; n0++) {
      int col = n0 * 16 + l15;
      if (col < CD) {
        float bias = fcb[col];
#pragma unroll
        for (int r2 = 0; r2 < 4; r2++) {
          int row = orow + r2;
          if (row < NN) {
            size_t idx = (size_t)row * CD + col;
            float v = accf[n0][r2] + bias;
            out[idx] = INIT ? v : out[idx] + v;
          }
        }
      }
    }
  } else {
    float bias[3];
#pragma unroll
    for (int n0 = 0; n0 < 3; n0++) {
      int col = n0 * 16 + l15;
      bias[n0] = (col < CD) ? fcb[col] : 0.f;
    }
#pragma unroll
    for (int r2 = 0; r2 < 4; r2++) {
      int row = orow + r2;
      float v[3];
#pragma unroll
      for (int n0 = 0; n0 < 3; n0++) {
        int col = n0 * 16 + l15;
        if (col < CD) {
          float prev = (row < NN) ? out[(size_t)row * CD + col] : 0.f;
          v[n0] = prev + accf[n0][r2] + bias[n0];
        } else {
          v[n0] = -1e30f;
        }
      }
      float m = fmaxf(v[0], fmaxf(v[1], v[2]));
#pragma unroll
      for (int s = 1; s < 16; s <<= 1) m = fmaxf(m, __shfl_xor(m, s, 64));
      float sum = 0.f;
#pragma unroll
      for (int n0 = 0; n0 < 3; n0++) {
        int col = n0 * 16 + l15;
        if (col < CD) sum += __expf(v[n0] - m);
      }
#pragma unroll
      for (int s = 1; s < 16; s <<= 1) sum += __shfl_xor(sum, s, 64);
      float ls = m + logf(sum);
      if (row < NN) {
#pragma unroll
        for (int n0 = 0; n0 < 3; n0++) {
          int col = n0 * 16 + l15;
          if (col < CD) out[(size_t)row * CD + col] = v[n0] - ls;
        }
      }
    }
  }
}

// ---------- CSR gather: (node, column-half) tasks; XCD-parity affinity via blockIdx&1 ----------
// half h_col = bid&1 rides the round-robin block->XCD mapping: even XCDs see only
// half 0's 12.8 MB slice. Wave = 1 node-half: 8 lanes x uint4 = 128B half-row,
// 8 edges in flight per load instruction. No queue / no barriers / no atomics.
__launch_bounds__(256)
__global__ void k_gather(const uint4* __restrict__ xw, const int2* __restrict__ rse,
                         const unsigned int* __restrict__ csrp, const float* __restrict__ dinv,
                         uint4* __restrict__ aggb) {
  int tid = threadIdx.x;
  int bid = blockIdx.x;
  int hcol = bid & 1;               // column half -> XCD parity
  int n = (bid >> 1) * 4 + (tid >> 6);
  int l = tid & 63;
  int h = l >> 3, cl = l & 7;       // 8 edge-slots x 8 lanes x 16B = 128B half-row
  int ro = hcol * 8 + cl;           // uint4 index within 256B row
  float dn = dinv[n];
  float kk = dn * (1.0f / 32768.0f);
  uint4 u = xw[n * 16 + ro];
  float cs = (h == 0) ? 2.0f * dn * dn : 0.0f;
  float a0 = cs * lo16(u.x), a1 = cs * hi16(u.x);
  float a2 = cs * lo16(u.y), a3 = cs * hi16(u.y);
  float a4 = cs * lo16(u.z), a5 = cs * hi16(u.z);
  float a6 = cs * lo16(u.w), a7 = cs * hi16(u.w);
  int2 r = rse[n];
  int e = r.x, e1 = r.y;            // length multiple of 8
  for (; e < e1; e += 8) {
    unsigned int p0 = csrp[e + h];
    uint4 v0 = xw[(p0 & 0x1FFFFu) * 16 + ro];
    float c0 = (float)(p0 >> 17) * kk;
    a0 += c0 * lo16(v0.x); a1 += c0 * hi16(v0.x);
    a2 += c0 * lo16(v0.y); a3 += c0 * hi16(v0.y);
    a4 += c0 * lo16(v0.z); a5 += c0 * hi16(v0.z);
    a6 += c0 * lo16(v0.w); a7 += c0 * hi16(v0.w);
  }
  a0 += __shfl_xor(a0, 8, 64); a0 += __shfl_xor(a0, 16, 64); a0 += __shfl_xor(a0, 32, 64);
  a1 += __shfl_xor(a1, 8, 64); a1 += __shfl_xor(a1, 16, 64); a1 += __shfl_xor(a1, 32, 64);
  a2 += __shfl_xor(a2, 8, 64); a2 += __shfl_xor(a2, 16, 64); a2 += __shfl_xor(a2, 32, 64);
  a3 += __shfl_xor(a3, 8, 64); a3 += __shfl_xor(a3, 16, 64); a3 += __shfl_xor(a3, 32, 64);
  a4 += __shfl_xor(a4, 8, 64); a4 += __shfl_xor(a4, 16, 64); a4 += __shfl_xor(a4, 32, 64);
  a5 += __shfl_xor(a5, 8, 64); a5 += __shfl_xor(a5, 16, 64); a5 += __shfl_xor(a5, 32, 64);
  a6 += __shfl_xor(a6, 8, 64); a6 += __shfl_xor(a6, 16, 64); a6 += __shfl_xor(a6, 32, 64);
  a7 += __shfl_xor(a7, 8, 64); a7 += __shfl_xor(a7, 16, 64); a7 += __shfl_xor(a7, 32, 64);
  if (h == 0) {
    uint4 o;
    o.x = (unsigned int)f2b(a0) | ((unsigned int)f2b(a1) << 16);
    o.y = (unsigned int)f2b(a2) | ((unsigned int)f2b(a3) << 16);
    o.z = (unsigned int)f2b(a4) | ((unsigned int)f2b(a5) << 16);
    o.w = (unsigned int)f2b(a6) | ((unsigned int)f2b(a7) << 16);
    aggb[n * 16 + ro] = o;
  }
}

// ---------- BN column stats from bf16 agg (separate, streaming — R8 form) ----------
__launch_bounds__(256)
__global__ void k_stats(const uint2* __restrict__ agg, float* __restrict__ statsL) {
  __shared__ float ls1[128], ls2[128];
  int tid = threadIdx.x;
  if (tid < 128) { ls1[tid] = 0.f; ls2[tid] = 0.f; }
  __syncthreads();
  int cl = tid & 31, rg = tid >> 5;
  float s10 = 0.f, s11 = 0.f, s12 = 0.f, s13 = 0.f;
  float s20 = 0.f, s21 = 0.f, s22 = 0.f, s23 = 0.f;
  for (int r = blockIdx.x * 8 + rg; r < NN; r += 2048) {
    uint2 u = agg[r * 32 + cl];
    float b0 = lo16(u.x), b1 = hi16(u.x), b2 = lo16(u.y), b3 = hi16(u.y);
    s10 += b0; s20 += b0 * b0;
    s11 += b1; s21 += b1 * b1;
    s12 += b2; s22 += b2 * b2;
    s13 += b3; s23 += b3 * b3;
  }
  atomicAdd(&ls1[4 * cl + 0], s10);
  atomicAdd(&ls1[4 * cl + 1], s11);
  atomicAdd(&ls1[4 * cl + 2], s12);
  atomicAdd(&ls1[4 * cl + 3], s13);
  atomicAdd(&ls2[4 * cl + 0], s20);
  atomicAdd(&ls2[4 * cl + 1], s21);
  atomicAdd(&ls2[4 * cl + 2], s22);
  atomicAdd(&ls2[4 * cl + 3], s23);
  __syncthreads();
  if (tid < 128) {
    float* st = statsL + (blockIdx.x & 3) * 256;
    atomicAdd(&st[tid], ls1[tid]);
    atomicAdd(&st[128 + tid], ls2[tid]);
  }
}

static inline size_t alup(size_t x) { return (x + 255) & ~(size_t)255; }

extern "C" void kernel_launch(void* const* d_in, const int* in_sizes, int n_in,
                              void* d_out, int out_size, void* d_ws, size_t ws_size,
                              hipStream_t stream) {
  char* p = (char*)d_ws;
  bf16* xwb = (bf16*)p;     p += alup((size_t)NN * FD * 2);
  bf16* aggb = (bf16*)p;    p += alup((size_t)NN * FD * 2);
  float* dinv = (float*)p;  p += alup((size_t)NN * 4);
  int2* rse = (int2*)p;     p += alup((size_t)NN * 8);
  int* gcur = (int*)p;      p += alup((size_t)NTB * 4);
  float* stats = (float*)p; p += alup((size_t)NL * 1024 * 4);
  unsigned int* csrE = (unsigned int*)p; p += alup((size_t)NTB * EBCAP * 4);
  unsigned int* csrp = (unsigned int*)p; p += alup((size_t)NTB * OCAP * 4);
  bf16* wp = (bf16*)p;      p += alup((size_t)NL * 16384 * 2);
  bf16* wpfc = (bf16*)p;    p += alup((size_t)5 * 6144 * 2);

  const float* x = (const float*)d_in[0];
  const int* ei = (const int*)d_in[1];
  const int* srcv = ei;
  const int* dstv = ei + NE;
  const float* convw = (const float*)d_in[2];
  const float* bng = (const float*)d_in[4];
  const float* bnb = (const float*)d_in[5];
  const float* fcw = (const float*)d_in[6];
  const float* fcb = (const float*)d_in[7];
  float* out = (float*)d_out;

  // one memset over contiguous gcur + stats
  hipMemsetAsync(gcur, 0, alup((size_t)NTB * 4) + alup((size_t)NL * 1024 * 4), stream);
  // build pass 1 + weight repack (independent halves of one grid)
  k_bfill<<<NTILES + RPB, 256, 0, stream>>>(srcv, dstv, gcur, csrE, convw, fcw, wp, wpfc);
  k_bsort<<<NTB, 256, 0, stream>>>(gcur, csrE, csrp, dinv, rse);
  // layer-0 conv GEMM + fc head (out init) + merged coef pre-pack
  k_gfc<8, false, true, false, true><<<GFCB + PKB, 256, 0, stream>>>(
      x, nullptr, nullptr, nullptr, wp, wpfc, fcb, xwb, out, csrp, dinv);

  for (int L = 0; L < NL; L++) {
    float* st = stats + (size_t)L * 1024;
    k_gather<<<NN / 2, 256, 0, stream>>>((const uint4*)xwb, rse, csrp, dinv,
                                         (uint4*)aggb);
    k_stats<<<256, 256, 0, stream>>>((const uint2*)aggb, st);
    if (L < NL - 1) {
      k_gfc<8, true, false, false, false><<<GFCB, 256, 0, stream>>>(
          aggb, st, bng + L * FD, bnb + L * FD,
          wp + (size_t)(L + 1) * 16384, wpfc + (size_t)(L + 1) * 6144,
          fcb + (L + 1) * CD, xwb, out, nullptr, nullptr);
    } else {
      k_gfc<0, true, false, true, false><<<GFCB, 256, 0, stream>>>(
          aggb, st, bng + L * FD, bnb + L * FD,
          nullptr, wpfc + (size_t)(L + 1) * 6144,
          fcb + (L + 1) * CD, nullptr, out, nullptr, nullptr);
    }
  }
}

// Round 11
// 572.151 us; speedup vs baseline: 1.6364x; 1.1519x over previous
//
#include <hip/hip_runtime.h>
#include <hip/hip_bf16.h>
#include <stdint.h>

#define NN 100000
#define NE 1600000
#define FD 128
#define CD 40
#define NL 4
#define NTB 391        // coarse buckets of 256 nodes (391*256 = 100096)
#define TILE 4096      // edges per staging block
#define NTILES 391     // ceil(NE/TILE)
#define EBCAP 8192     // per-bucket staged region (entries incl. 16-pad)
#define OCAP 5632      // per-bucket csr region (real+pad8)
#define RPB 376        // repack blocks: (NL*16384 + 5*6144)/256
#define PKB 512        // pack blocks (grid-strided)
#define GFCB 1563      // gfc grid (64 rows/block)

typedef __bf16 bf16;
typedef __bf16 bf16x8 __attribute__((ext_vector_type(8)));
typedef float f32x4 __attribute__((ext_vector_type(4)));

__device__ __forceinline__ unsigned short f2b(float f) {
  bf16 b = (bf16)f;
  unsigned short u;
  __builtin_memcpy(&u, &b, 2);
  return u;
}
__device__ __forceinline__ float lo16(unsigned int u) { return __uint_as_float(u << 16); }
__device__ __forceinline__ float hi16(unsigned int u) { return __uint_as_float(u & 0xffff0000u); }

// ---------- pass 1: LDS-staged binning + (merged) weight repack ----------
__launch_bounds__(256)
__global__ void k_bfill(const int* __restrict__ src, const int* __restrict__ dst,
                        int* __restrict__ gcur, unsigned int* __restrict__ csrE,
                        const float* __restrict__ wc, const float* __restrict__ wf,
                        bf16* __restrict__ wp, bf16* __restrict__ wpfc) {
  __shared__ int cnt[NTB], pref[NTB], gofs[NTB];
  __shared__ int sc[512];
  __shared__ unsigned int stage[TILE];
  __shared__ unsigned short tgtb[TILE];
  int tid = threadIdx.x;
  if (blockIdx.x >= NTILES) {
    int t = (blockIdx.x - NTILES) * 256 + tid;
    if (t < NL * 16384) {
      int j = t & 7, lane = (t >> 3) & 63, n0 = (t >> 9) & 7, k0 = (t >> 12) & 3, layer = t >> 14;
      int k = k0 * 32 + (lane >> 4) * 8 + j;
      int n = n0 * 16 + (lane & 15);
      wp[t] = (bf16)wc[(layer * 128 + k) * 128 + n];
    } else {
      t -= NL * 16384;
      if (t < 5 * 6144) {
        int j = t & 7, lane = (t >> 3) & 63;
        int rest = t >> 9;
        int n0 = rest % 3;
        int rest2 = rest / 3;
        int k0 = rest2 & 3, layer = rest2 >> 2;
        int k = k0 * 32 + (lane >> 4) * 8 + j;
        int n = n0 * 16 + (lane & 15);
        wpfc[t] = (n < CD) ? (bf16)wf[(layer * 128 + k) * CD + n] : (bf16)0.0f;
      }
    }
    return;
  }
  int base = blockIdx.x * TILE;
  int tcnt = min(TILE, NE - base);
  for (int b = tid; b < NTB; b += 256) cnt[b] = 0;
  __syncthreads();
  unsigned int pay[16];
  int brk[16];
#pragma unroll
  for (int i = 0; i < 16; i++) {
    int e = base + tid + i * 256;
    if (e < NE) {
      int d = dst[e];
      int b = d >> 8;
      int r = atomicAdd(&cnt[b], 1);
      pay[i] = (unsigned int)src[e] | ((unsigned int)(d & 255) << 17);
      brk[i] = (b << 12) | r;
    } else {
      brk[i] = -1;
    }
  }
  __syncthreads();
  sc[tid] = (tid < NTB) ? cnt[tid] : 0;
  sc[tid + 256] = (tid + 256 < NTB) ? cnt[tid + 256] : 0;
  __syncthreads();
  for (int off = 1; off < 512; off <<= 1) {
    int a0 = (tid >= off) ? sc[tid - off] : 0;
    int a1 = sc[tid + 256 - off];
    __syncthreads();
    sc[tid] += a0;
    sc[tid + 256] += a1;
    __syncthreads();
  }
  for (int b = tid; b < NTB; b += 256) pref[b] = sc[b] - cnt[b];
  __syncthreads();
#pragma unroll
  for (int i = 0; i < 16; i++) {
    if (brk[i] >= 0) {
      int b = brk[i] >> 12, r = brk[i] & 4095;
      int p = pref[b] + r;
      if ((unsigned)p < (unsigned)TILE) {
        stage[p] = pay[i];
        tgtb[p] = (unsigned short)b;
      }
    }
  }
  for (int b = tid; b < NTB; b += 256) {
    int c = cnt[b];
    gofs[b] = c ? atomicAdd(&gcur[b], (c + 15) & ~15) : 0;
  }
  __syncthreads();
  for (int t = tid; t < tcnt; t += 256) {
    int b = tgtb[t];
    int pos = gofs[b] + (t - pref[b]);
    if ((unsigned)pos < (unsigned)EBCAP) csrE[(size_t)b * EBCAP + pos] = stage[t];
  }
  for (int b = tid; b < NTB; b += 256) {
    int c = cnt[b];
    if (c) {
      int pad = (c + 15) & ~15;
      for (int j = c; j < pad; j++) {
        int pos = gofs[b] + j;
        if ((unsigned)pos < (unsigned)EBCAP) csrE[(size_t)b * EBCAP + pos] = 0xFFFFFFFFu;
      }
    }
  }
}

// ---------- pass 2: per-bucket counting sort; per-node lists padded to x8 ----------
__launch_bounds__(256)
__global__ void k_bsort(const int* __restrict__ gcur, const unsigned int* __restrict__ csrE,
                        unsigned int* __restrict__ csrp, float* __restrict__ dinv,
                        int2* __restrict__ rse) {
  __shared__ unsigned int ent[OCAP];
  __shared__ int c32[256], prefn[256], c2[256], sc[256];
  __shared__ int ecnt_s;
  int b = blockIdx.x, tid = threadIdx.x;
  c32[tid] = 0;
  c2[tid] = 0;
  if (tid == 0) ecnt_s = 0;
  __syncthreads();
  int claimed = min(gcur[b], EBCAP);
  const unsigned int* in = csrE + (size_t)b * EBCAP;
  for (int i = tid; i < claimed; i += 256) {
    unsigned int e = in[i];
    if (e != 0xFFFFFFFFu) {
      int idx = atomicAdd(&ecnt_s, 1);
      if (idx < OCAP) ent[idx] = e;
      atomicAdd(&c32[e >> 17], 1);
    }
  }
  __syncthreads();
  int cnt = min(ecnt_s, OCAP);
  int c = c32[tid];
  int pc = (c + 7) & ~7;           // padded-to-multiple-of-8 length
  sc[tid] = pc;
  __syncthreads();
  for (int off = 1; off < 256; off <<= 1) {
    int a = (tid >= off) ? sc[tid - off] : 0;
    __syncthreads();
    sc[tid] += a;
    __syncthreads();
  }
  prefn[tid] = sc[tid] - pc;
  int node = b * 256 + tid;
  if (node < NN) {
    dinv[node] = rsqrtf((float)c + 2.0f);
    int s = b * OCAP + prefn[tid];
    rse[node] = make_int2(s, s + pc);
  }
  for (int j = c; j < pc; j++) {
    int pos = prefn[tid] + j;
    if (pos < OCAP) csrp[b * OCAP + pos] = 0x1FFFFu;
  }
  __syncthreads();
  for (int i = tid; i < cnt; i += 256) {
    unsigned int e = ent[i];
    int dlo = e >> 17;
    int ofs = atomicAdd(&c2[dlo], 1);
    int pos = prefn[dlo] + ofs;
    if (pos < OCAP) csrp[b * OCAP + pos] = e & 0x1FFFFu;
  }
}

// ---------- fused (BN+ReLU) -> [conv GEMM | FC head (+log_softmax)] (+merged pack) ----------
template <int NC, bool BN, bool INIT, bool LSM, bool PACK>
__launch_bounds__(256)
__global__ void k_gfc(const void* __restrict__ inp, const float* __restrict__ stats,
                      const float* __restrict__ g, const float* __restrict__ bb,
                      const bf16* __restrict__ wconv, const bf16* __restrict__ wfc,
                      const float* __restrict__ fcb, bf16* __restrict__ xwb,
                      float* __restrict__ out,
                      unsigned int* __restrict__ csrp, const float* __restrict__ dinvp) {
  __shared__ bf16 wl[NC * 2048 + 6144];
  __shared__ float sc[128], sh[128];
  int tid = threadIdx.x;
  if (PACK && blockIdx.x >= GFCB) {
    for (int i = (blockIdx.x - GFCB) * 256 + tid; i < NTB * OCAP; i += PKB * 256) {
      unsigned int e = csrp[i];
      unsigned int s = e & 0x1FFFFu;
      unsigned int fix = 0;
      if (s < NN) {
        fix = (unsigned int)__float2uint_rn(dinvp[s] * 32768.0f);
      } else {
        s = 0;
      }
      csrp[i] = (fix << 17) | s;
    }
    return;
  }
  if (NC) {
    const uint4* gc = (const uint4*)wconv;
    uint4* lc = (uint4*)wl;
#pragma unroll
    for (int i = 0; i < NC; i++) lc[tid + i * 256] = gc[tid + i * 256];
  }
  {
    const uint4* gf = (const uint4*)wfc;
    uint4* lf = (uint4*)(wl + NC * 2048);
    for (int i = tid; i < 768; i += 256) lf[i] = gf[i];
  }
  if (BN && tid < 128) {
    const float invN = 1.0f / (float)NN;
    float s1 = stats[tid] + stats[256 + tid] + stats[512 + tid] + stats[768 + tid];
    float s2 = stats[128 + tid] + stats[384 + tid] + stats[640 + tid] + stats[896 + tid];
    float mu = s1 * invN;
    float var = s2 * invN - mu * mu;
    float s = g[tid] * rsqrtf(var + 1e-5f);
    sc[tid] = s;
    sh[tid] = bb[tid] - mu * s;
  }
  __syncthreads();
  int wid = tid >> 6, lane = tid & 63, quad = lane >> 4, l15 = lane & 15;
  int m_base = blockIdx.x * 64 + wid * 16;
  int arow = m_base + l15;
  if (arow >= NN) arow = NN - 1;
  f32x4 accc[NC > 0 ? NC : 1];
  f32x4 accf[3];
  if (NC) {
#pragma unroll
    for (int i = 0; i < NC; i++) accc[i] = (f32x4){0.f, 0.f, 0.f, 0.f};
  }
#pragma unroll
  for (int i = 0; i < 3; i++) accf[i] = (f32x4){0.f, 0.f, 0.f, 0.f};
#pragma unroll
  for (int k0 = 0; k0 < 4; k0++) {
    union Fr { bf16x8 v; unsigned short us[8]; } fr;
    if (BN) {
      const uint4* prow = (const uint4*)((const bf16*)inp + (size_t)arow * 128 + k0 * 32 + quad * 8);
      uint4 u = *prow;
      unsigned int uu[4] = {u.x, u.y, u.z, u.w};
      int kc = k0 * 32 + quad * 8;
#pragma unroll
      for (int p = 0; p < 4; p++) {
        float x0 = lo16(uu[p]) * sc[kc + 2 * p] + sh[kc + 2 * p];
        float x1 = hi16(uu[p]) * sc[kc + 2 * p + 1] + sh[kc + 2 * p + 1];
        fr.us[2 * p] = f2b(fmaxf(0.f, x0));
        fr.us[2 * p + 1] = f2b(fmaxf(0.f, x1));
      }
    } else {
      const float* prow = (const float*)inp + (size_t)arow * 128 + k0 * 32 + quad * 8;
      float4 u0 = *(const float4*)prow;
      float4 u1 = *(const float4*)(prow + 4);
      fr.us[0] = f2b(u0.x); fr.us[1] = f2b(u0.y); fr.us[2] = f2b(u0.z); fr.us[3] = f2b(u0.w);
      fr.us[4] = f2b(u1.x); fr.us[5] = f2b(u1.y); fr.us[6] = f2b(u1.z); fr.us[7] = f2b(u1.w);
    }
    bf16x8 a = fr.v;
    if (NC) {
#pragma unroll
      for (int n0 = 0; n0 < NC; n0++) {
        bf16x8 bfr = *reinterpret_cast<const bf16x8*>(&wl[(k0 * NC + n0) * 512 + lane * 8]);
        accc[n0] = __builtin_amdgcn_mfma_f32_16x16x32_bf16(a, bfr, accc[n0], 0, 0, 0);
      }
    }
#pragma unroll
    for (int n0 = 0; n0 < 3; n0++) {
      bf16x8 bfr = *reinterpret_cast<const bf16x8*>(&wl[NC * 2048 + (k0 * 3 + n0) * 512 + lane * 8]);
      accf[n0] = __builtin_amdgcn_mfma_f32_16x16x32_bf16(a, bfr, accf[n0], 0, 0, 0);
    }
  }
  int orow = m_base + quad * 4;
  if (NC) {
#pragma unroll
    for (int n0 = 0; n0 < NC; n0++) {
#pragma unroll
      for (int r2 = 0; r2 < 4; r2++) {
        int row = orow + r2;
        if (row < NN) xwb[(size_t)row * 128 + n0 * 16 + l15] = (bf16)accc[n0][r2];
      }
    }
  }
  if (!LSM) {
#pragma unroll
    for (int n0 = 0; n0 < 3; n0++) {
      int col = n0 * 16 + l15;
      if (col < CD) {
        float bias = fcb[col];
#pragma unroll
        for (int r2 = 0; r2 < 4; r2++) {
          int row = orow + r2;
          if (row < NN) {
            size_t idx = (size_t)row * CD + col;
            float v = accf[n0][r2] + bias;
            out[idx] = INIT ? v : out[idx] + v;
          }
        }
      }
    }
  } else {
    float bias[3];
#pragma unroll
    for (int n0 = 0; n0 < 3; n0++) {
      int col = n0 * 16 + l15;
      bias[n0] = (col < CD) ? fcb[col] : 0.f;
    }
#pragma unroll
    for (int r2 = 0; r2 < 4; r2++) {
      int row = orow + r2;
      float v[3];
#pragma unroll
      for (int n0 = 0; n0 < 3; n0++) {
        int col = n0 * 16 + l15;
        if (col < CD) {
          float prev = (row < NN) ? out[(size_t)row * CD + col] : 0.f;
          v[n0] = prev + accf[n0][r2] + bias[n0];
        } else {
          v[n0] = -1e30f;
        }
      }
      float m = fmaxf(v[0], fmaxf(v[1], v[2]));
#pragma unroll
      for (int s = 1; s < 16; s <<= 1) m = fmaxf(m, __shfl_xor(m, s, 64));
      float sum = 0.f;
#pragma unroll
      for (int n0 = 0; n0 < 3; n0++) {
        int col = n0 * 16 + l15;
        if (col < CD) sum += __expf(v[n0] - m);
      }
#pragma unroll
      for (int s = 1; s < 16; s <<= 1) sum += __shfl_xor(sum, s, 64);
      float ls = m + logf(sum);
      if (row < NN) {
#pragma unroll
        for (int n0 = 0; n0 < 3; n0++) {
          int col = n0 * 16 + l15;
          if (col < CD) out[(size_t)row * CD + col] = v[n0] - ls;
        }
      }
    }
  }
}

// ---------- CSR gather: 1 wave = 1 node; uint4 loads; 16 edges/iter (4 rows in flight) ----------
__launch_bounds__(256)
__global__ void k_gather(const uint4* __restrict__ xw, const int2* __restrict__ rse,
                         const unsigned int* __restrict__ csrp, const float* __restrict__ dinv,
                         uint4* __restrict__ aggb) {
  int tid = threadIdx.x;
  int n = blockIdx.x * 4 + (tid >> 6);
  int l = tid & 63;
  int h = l >> 4, cl = l & 15;    // 4 edge-slots x 16 lanes x 16B = 256B row
  float dn = dinv[n];
  float kk = dn * (1.0f / 32768.0f);
  uint4 u = xw[n * 16 + cl];
  float cs = (h == 0) ? 2.0f * dn * dn : 0.0f;
  float a0 = cs * lo16(u.x), a1 = cs * hi16(u.x);
  float a2 = cs * lo16(u.y), a3 = cs * hi16(u.y);
  float a4 = cs * lo16(u.z), a5 = cs * hi16(u.z);
  float a6 = cs * lo16(u.w), a7 = cs * hi16(u.w);
  int2 r = rse[n];
  int e = r.x, e1 = r.y;   // length multiple of 8
  for (; e + 15 < e1; e += 16) {
    unsigned int p0 = csrp[e + h];
    unsigned int p1 = csrp[e + 4 + h];
    unsigned int p2 = csrp[e + 8 + h];
    unsigned int p3 = csrp[e + 12 + h];
    uint4 v0 = xw[(p0 & 0x1FFFFu) * 16 + cl];
    uint4 v1 = xw[(p1 & 0x1FFFFu) * 16 + cl];
    uint4 v2 = xw[(p2 & 0x1FFFFu) * 16 + cl];
    uint4 v3 = xw[(p3 & 0x1FFFFu) * 16 + cl];
    float c0 = (float)(p0 >> 17) * kk;
    float c1 = (float)(p1 >> 17) * kk;
    float c2 = (float)(p2 >> 17) * kk;
    float c3 = (float)(p3 >> 17) * kk;
    a0 += c0 * lo16(v0.x); a1 += c0 * hi16(v0.x);
    a2 += c0 * lo16(v0.y); a3 += c0 * hi16(v0.y);
    a4 += c0 * lo16(v0.z); a5 += c0 * hi16(v0.z);
    a6 += c0 * lo16(v0.w); a7 += c0 * hi16(v0.w);
    a0 += c1 * lo16(v1.x); a1 += c1 * hi16(v1.x);
    a2 += c1 * lo16(v1.y); a3 += c1 * hi16(v1.y);
    a4 += c1 * lo16(v1.z); a5 += c1 * hi16(v1.z);
    a6 += c1 * lo16(v1.w); a7 += c1 * hi16(v1.w);
    a0 += c2 * lo16(v2.x); a1 += c2 * hi16(v2.x);
    a2 += c2 * lo16(v2.y); a3 += c2 * hi16(v2.y);
    a4 += c2 * lo16(v2.z); a5 += c2 * hi16(v2.z);
    a6 += c2 * lo16(v2.w); a7 += c2 * hi16(v2.w);
    a0 += c3 * lo16(v3.x); a1 += c3 * hi16(v3.x);
    a2 += c3 * lo16(v3.y); a3 += c3 * hi16(v3.y);
    a4 += c3 * lo16(v3.z); a5 += c3 * hi16(v3.z);
    a6 += c3 * lo16(v3.w); a7 += c3 * hi16(v3.w);
  }
  if (e < e1) {          // tail: exactly 8 edges (length % 16 == 8)
    unsigned int p0 = csrp[e + h];
    unsigned int p1 = csrp[e + 4 + h];
    uint4 v0 = xw[(p0 & 0x1FFFFu) * 16 + cl];
    uint4 v1 = xw[(p1 & 0x1FFFFu) * 16 + cl];
    float c0 = (float)(p0 >> 17) * kk;
    float c1 = (float)(p1 >> 17) * kk;
    a0 += c0 * lo16(v0.x); a1 += c0 * hi16(v0.x);
    a2 += c0 * lo16(v0.y); a3 += c0 * hi16(v0.y);
    a4 += c0 * lo16(v0.z); a5 += c0 * hi16(v0.z);
    a6 += c0 * lo16(v0.w); a7 += c0 * hi16(v0.w);
    a0 += c1 * lo16(v1.x); a1 += c1 * hi16(v1.x);
    a2 += c1 * lo16(v1.y); a3 += c1 * hi16(v1.y);
    a4 += c1 * lo16(v1.z); a5 += c1 * hi16(v1.z);
    a6 += c1 * lo16(v1.w); a7 += c1 * hi16(v1.w);
  }
  a0 += __shfl_xor(a0, 16, 64); a0 += __shfl_xor(a0, 32, 64);
  a1 += __shfl_xor(a1, 16, 64); a1 += __shfl_xor(a1, 32, 64);
  a2 += __shfl_xor(a2, 16, 64); a2 += __shfl_xor(a2, 32, 64);
  a3 += __shfl_xor(a3, 16, 64); a3 += __shfl_xor(a3, 32, 64);
  a4 += __shfl_xor(a4, 16, 64); a4 += __shfl_xor(a4, 32, 64);
  a5 += __shfl_xor(a5, 16, 64); a5 += __shfl_xor(a5, 32, 64);
  a6 += __shfl_xor(a6, 16, 64); a6 += __shfl_xor(a6, 32, 64);
  a7 += __shfl_xor(a7, 16, 64); a7 += __shfl_xor(a7, 32, 64);
  if (h == 0) {
    uint4 o;
    o.x = (unsigned int)f2b(a0) | ((unsigned int)f2b(a1) << 16);
    o.y = (unsigned int)f2b(a2) | ((unsigned int)f2b(a3) << 16);
    o.z = (unsigned int)f2b(a4) | ((unsigned int)f2b(a5) << 16);
    o.w = (unsigned int)f2b(a6) | ((unsigned int)f2b(a7) << 16);
    aggb[n * 16 + cl] = o;
  }
}

// ---------- BN column stats from bf16 agg (separate, streaming) ----------
__launch_bounds__(256)
__global__ void k_stats(const uint2* __restrict__ agg, float* __restrict__ statsL) {
  __shared__ float ls1[128], ls2[128];
  int tid = threadIdx.x;
  if (tid < 128) { ls1[tid] = 0.f; ls2[tid] = 0.f; }
  __syncthreads();
  int cl = tid & 31, rg = tid >> 5;
  float s10 = 0.f, s11 = 0.f, s12 = 0.f, s13 = 0.f;
  float s20 = 0.f, s21 = 0.f, s22 = 0.f, s23 = 0.f;
  for (int r = blockIdx.x * 8 + rg; r < NN; r += 2048) {
    uint2 u = agg[r * 32 + cl];
    float b0 = lo16(u.x), b1 = hi16(u.x), b2 = lo16(u.y), b3 = hi16(u.y);
    s10 += b0; s20 += b0 * b0;
    s11 += b1; s21 += b1 * b1;
    s12 += b2; s22 += b2 * b2;
    s13 += b3; s23 += b3 * b3;
  }
  atomicAdd(&ls1[4 * cl + 0], s10);
  atomicAdd(&ls1[4 * cl + 1], s11);
  atomicAdd(&ls1[4 * cl + 2], s12);
  atomicAdd(&ls1[4 * cl + 3], s13);
  atomicAdd(&ls2[4 * cl + 0], s20);
  atomicAdd(&ls2[4 * cl + 1], s21);
  atomicAdd(&ls2[4 * cl + 2], s22);
  atomicAdd(&ls2[4 * cl + 3], s23);
  __syncthreads();
  if (tid < 128) {
    float* st = statsL + (blockIdx.x & 3) * 256;
    atomicAdd(&st[tid], ls1[tid]);
    atomicAdd(&st[128 + tid], ls2[tid]);
  }
}

static inline size_t alup(size_t x) { return (x + 255) & ~(size_t)255; }

extern "C" void kernel_launch(void* const* d_in, const int* in_sizes, int n_in,
                              void* d_out, int out_size, void* d_ws, size_t ws_size,
                              hipStream_t stream) {
  char* p = (char*)d_ws;
  bf16* xwb = (bf16*)p;     p += alup((size_t)NN * FD * 2);
  bf16* aggb = (bf16*)p;    p += alup((size_t)NN * FD * 2);
  float* dinv = (float*)p;  p += alup((size_t)NN * 4);
  int2* rse = (int2*)p;     p += alup((size_t)NN * 8);
  int* gcur = (int*)p;      p += alup((size_t)NTB * 4);
  float* stats = (float*)p; p += alup((size_t)NL * 1024 * 4);
  unsigned int* csrE = (unsigned int*)p; p += alup((size_t)NTB * EBCAP * 4);
  unsigned int* csrp = (unsigned int*)p; p += alup((size_t)NTB * OCAP * 4);
  bf16* wp = (bf16*)p;      p += alup((size_t)NL * 16384 * 2);
  bf16* wpfc = (bf16*)p;    p += alup((size_t)5 * 6144 * 2);

  const float* x = (const float*)d_in[0];
  const int* ei = (const int*)d_in[1];
  const int* srcv = ei;
  const int* dstv = ei + NE;
  const float* convw = (const float*)d_in[2];
  const float* bng = (const float*)d_in[4];
  const float* bnb = (const float*)d_in[5];
  const float* fcw = (const float*)d_in[6];
  const float* fcb = (const float*)d_in[7];
  float* out = (float*)d_out;

  // one memset over contiguous gcur + stats
  hipMemsetAsync(gcur, 0, alup((size_t)NTB * 4) + alup((size_t)NL * 1024 * 4), stream);
  // build pass 1 + weight repack (independent halves of one grid)
  k_bfill<<<NTILES + RPB, 256, 0, stream>>>(srcv, dstv, gcur, csrE, convw, fcw, wp, wpfc);
  k_bsort<<<NTB, 256, 0, stream>>>(gcur, csrE, csrp, dinv, rse);
  // layer-0 conv GEMM + fc head (out init) + merged coef pre-pack
  k_gfc<8, false, true, false, true><<<GFCB + PKB, 256, 0, stream>>>(
      x, nullptr, nullptr, nullptr, wp, wpfc, fcb, xwb, out, csrp, dinv);

  for (int L = 0; L < NL; L++) {
    float* st = stats + (size_t)L * 1024;
    k_gather<<<NN / 4, 256, 0, stream>>>((const uint4*)xwb, rse, csrp, dinv,
                                         (uint4*)aggb);
    k_stats<<<256, 256, 0, stream>>>((const uint2*)aggb, st);
    if (L < NL - 1) {
      k_gfc<8, true, false, false, false><<<GFCB, 256, 0, stream>>>(
          aggb, st, bng + L * FD, bnb + L * FD,
          wp + (size_t)(L + 1) * 16384, wpfc + (size_t)(L + 1) * 6144,
          fcb + (L + 1) * CD, xwb, out, nullptr, nullptr);
    } else {
      k_gfc<0, true, false, true, false><<<GFCB, 256, 0, stream>>>(
          aggb, st, bng + L * FD, bnb + L * FD,
          nullptr, wpfc + (size_t)(L + 1) * 6144,
          fcb + (L + 1) * CD, nullptr, out, nullptr, nullptr);
    }
  }
}